// Round 1
// baseline (616.310 us; speedup 1.0000x reference)
//
#include <hip/hip_runtime.h>
#include <stdint.h>
#include <stddef.h>

// ---------- types / helpers ----------
typedef __attribute__((ext_vector_type(8))) short bf16x8;   // 8 bf16 in 4 VGPRs
typedef __attribute__((ext_vector_type(4))) float f32x4;

typedef __attribute__((address_space(1))) unsigned int uint_g;
typedef __attribute__((address_space(3))) unsigned int uint_l;

#define DEV static __device__ __forceinline__

DEV unsigned short f2bf(float f) {          // RNE float -> bf16 bits
  unsigned int u = __float_as_uint(f);
  u += 0x7FFFu + ((u >> 16) & 1u);
  return (unsigned short)(u >> 16);
}
DEV float bf2f(unsigned short b) { return __uint_as_float(((unsigned int)b) << 16); }

DEV void gl_lds16(const unsigned short* g, unsigned short* l) {
  // async global->LDS, 16B per lane; LDS dest = wave-uniform base + lane*16
  __builtin_amdgcn_global_load_lds((const uint_g*)g, (uint_l*)l, 16, 0, 0);
}

// ---------- elementwise f32 -> bf16 (vectorized x4) ----------
__global__ __launch_bounds__(256) void k_f32_to_bf16(const float* __restrict__ in,
                                                     unsigned short* __restrict__ out, int n4) {
  int i = blockIdx.x * 256 + threadIdx.x;
  if (i >= n4) return;
  const float4 v = ((const float4*)in)[i];
  ushort4 o;
  o.x = f2bf(v.x); o.y = f2bf(v.y); o.z = f2bf(v.z); o.w = f2bf(v.w);
  ((ushort4*)out)[i] = o;
}

// ---------- transpose fp32 [R][C] -> bf16 [C][R] ----------
__global__ __launch_bounds__(256) void k_transpose_to_bf16(const float* __restrict__ in,
                                                           unsigned short* __restrict__ out,
                                                           int R, int C) {
  __shared__ unsigned short tile[32][33];   // +1 pad breaks bank conflicts
  const int c0 = blockIdx.x << 5, r0 = blockIdx.y << 5;
  const int tx = threadIdx.x & 31, ty = threadIdx.x >> 5;   // 32x8
  #pragma unroll
  for (int i = 0; i < 32; i += 8)
    tile[ty + i][tx] = f2bf(in[(size_t)(r0 + ty + i) * C + c0 + tx]);
  __syncthreads();
  #pragma unroll
  for (int i = 0; i < 32; i += 8)
    out[(size_t)(c0 + ty + i) * R + r0 + tx] = tile[tx][ty + i];
}

// ---------- generic bf16 MFMA GEMM: C = A @ B^T (+epilogue) ----------
// A: [M][K] bf16 row-major (lda), B: [N][K] bf16 row-major (ldb).
// Batched via blockIdx.z: off = (z>>3)*hi + (z&7)*lo  (elements).
// m97 structure: 2-barrier K-loop, global_load_lds w16, unpadded [rows][32] LDS,
// ds_read_b128 fragments, 16x16x32 MFMA, fp32 accum.
enum { EPI_BIAS = 0, EPI_SCALE = 1, EPI_PLAIN = 2, EPI_VT = 3, EPI_DUAL = 4,
       EPI_RELU = 5, EPI_RES = 6 };

template <int BM, int BN, int EPI>
__global__ __launch_bounds__(256)
void k_gemm(const unsigned short* __restrict__ A, const unsigned short* __restrict__ B,
            int lda, int ldb, int kSteps,
            size_t sAhi, size_t sAlo, size_t sBhi, size_t sBlo, size_t sChi, size_t sClo,
            void* C0, void* C1, const float* bias, const float* resid, int ldc) {
  constexpr int TM = BM / 32;   // acc tiles per wave (m) : wave tile = (BM/2)x(BN/2)
  constexpr int TN = BN / 32;
  __shared__ unsigned short At[BM * 32];
  __shared__ unsigned short Bt[BN * 32];

  const int t = threadIdx.x;
  const int lane = t & 63, wave = t >> 6;
  const int wm = wave >> 1, wn = wave & 1;            // 2x2 wave grid
  const int z = blockIdx.z;
  const size_t offA = (size_t)(z >> 3) * sAhi + (size_t)(z & 7) * sAlo;
  const size_t offB = (size_t)(z >> 3) * sBhi + (size_t)(z & 7) * sBlo;
  const size_t offC = (size_t)(z >> 3) * sChi + (size_t)(z & 7) * sClo;

  const unsigned short* Ab = A + offA + (size_t)blockIdx.y * BM * lda;
  const unsigned short* Bb = B + offB + (size_t)blockIdx.x * BN * ldb;

  const int frow = lane & 15, fk = (lane >> 4) << 3;  // fragment row / k-offset

  f32x4 acc[TM][TN] = {};

  for (int ks = 0; ks < kSteps; ++ks) {
    const int k0 = ks << 5;
    __syncthreads();                                   // prev frags consumed
    #pragma unroll
    for (int r = 0; r < BM / 64; ++r) {                // stage A tile (BM x 32)
      int off16 = (r << 8) + t;
      int row = off16 >> 2, kk = (off16 & 3) << 3;
      gl_lds16(Ab + (size_t)row * lda + k0 + kk, &At[(row << 5) + kk]);
    }
    #pragma unroll
    for (int r = 0; r < BN / 64; ++r) {                // stage B tile (BN x 32)
      int off16 = (r << 8) + t;
      int row = off16 >> 2, kk = (off16 & 3) << 3;
      gl_lds16(Bb + (size_t)row * ldb + k0 + kk, &Bt[(row << 5) + kk]);
    }
    __syncthreads();                                   // drains vmcnt, then barrier

    bf16x8 af[TM], bv[TN];
    #pragma unroll
    for (int mi = 0; mi < TM; ++mi)
      af[mi] = *(const bf16x8*)&At[((wm * (BM / 2) + mi * 16 + frow) << 5) + fk];
    #pragma unroll
    for (int ni = 0; ni < TN; ++ni)
      bv[ni] = *(const bf16x8*)&Bt[((wn * (BN / 2) + ni * 16 + frow) << 5) + fk];
    #pragma unroll
    for (int mi = 0; mi < TM; ++mi)
      #pragma unroll
      for (int ni = 0; ni < TN; ++ni)
        acc[mi][ni] = __builtin_amdgcn_mfma_f32_16x16x32_bf16(af[mi], bv[ni], acc[mi][ni], 0, 0, 0);
  }

  // C/D layout (m89-verified): col = lane&15, row = (lane>>4)*4 + reg
  const int mb = blockIdx.y * BM + wm * (BM / 2) + ((lane >> 4) << 2);
  const int nb = blockIdx.x * BN + wn * (BN / 2) + (lane & 15);

  #pragma unroll
  for (int mi = 0; mi < TM; ++mi) {
    const int m = mb + mi * 16;
    #pragma unroll
    for (int ni = 0; ni < TN; ++ni) {
      const int n = nb + ni * 16;
      f32x4 v = acc[mi][ni];
      if constexpr (EPI == EPI_BIAS) {                 // bf16(acc + bias[n])
        unsigned short* O = (unsigned short*)C0;
        const float bv2 = bias[n];
        #pragma unroll
        for (int r = 0; r < 4; ++r) O[offC + (size_t)(m + r) * ldc + n] = f2bf(v[r] + bv2);
      } else if constexpr (EPI == EPI_SCALE) {         // bf16(acc * 1/16) (scores)
        unsigned short* O = (unsigned short*)C0;
        #pragma unroll
        for (int r = 0; r < 4; ++r) O[offC + (size_t)(m + r) * ldc + n] = f2bf(v[r] * 0.0625f);
      } else if constexpr (EPI == EPI_PLAIN) {         // bf16(acc)
        unsigned short* O = (unsigned short*)C0;
        #pragma unroll
        for (int r = 0; r < 4; ++r) O[offC + (size_t)(m + r) * ldc + n] = f2bf(v[r]);
      } else if constexpr (EPI == EPI_VT) {            // V-proj -> Vt[b][h][d][li], +bias
        // m = b*576 + li (rows m..m+3 contiguous li, 576%4==0 so no b-crossing)
        const int b = m / 576, li = m - b * 576;
        const int h = n >> 8, d = n & 255;
        const float bv2 = bias[n];
        ushort4 o;
        o.x = f2bf(v[0] + bv2); o.y = f2bf(v[1] + bv2);
        o.z = f2bf(v[2] + bv2); o.w = f2bf(v[3] + bv2);
        *(ushort4*)((unsigned short*)C0 + ((size_t)((b * 8 + h) * 256 + d)) * 576 + li) = o;
      } else if constexpr (EPI == EPI_DUAL) {          // out-proj: fp32 + bf16 copies
        float* Of = (float*)C0;
        unsigned short* Ob = (unsigned short*)C1;
        const float bv2 = bias[n];
        #pragma unroll
        for (int r = 0; r < 4; ++r) {
          const float x = v[r] + bv2;
          const size_t idx = (size_t)(m + r) * ldc + n;
          Of[idx] = x; Ob[idx] = f2bf(x);
        }
      } else if constexpr (EPI == EPI_RELU) {          // ff1: bf16(relu(acc+bias))
        unsigned short* O = (unsigned short*)C0;
        const float bv2 = bias[n];
        #pragma unroll
        for (int r = 0; r < 4; ++r) {
          const float x = v[r] + bv2;
          O[(size_t)(m + r) * ldc + n] = f2bf(x > 0.f ? x : 0.f);
        }
      } else if constexpr (EPI == EPI_RES) {           // ff2: fp32(acc+bias+resid)
        float* Of = (float*)C0;
        const float bv2 = bias[n];
        #pragma unroll
        for (int r = 0; r < 4; ++r) {
          const size_t idx = (size_t)(m + r) * ldc + n;
          Of[idx] = v[r] + bv2 + resid[idx];
        }
      }
    }
  }
}

// ---------- softmax over rows of 576 bf16, in place; one wave per row ----------
__global__ __launch_bounds__(256) void k_softmax576(unsigned short* S) {
  const int row = (blockIdx.x << 2) + (threadIdx.x >> 6);
  const int lane = threadIdx.x & 63;
  unsigned int* rp = (unsigned int*)S + (size_t)row * 288;   // 576 bf16 = 288 dwords
  unsigned int u[5];
  u[0] = rp[lane]; u[1] = rp[lane + 64]; u[2] = rp[lane + 128]; u[3] = rp[lane + 192];
  const bool tail = lane < 32;
  u[4] = tail ? rp[lane + 256] : 0u;
  float a[10];
  #pragma unroll
  for (int j = 0; j < 5; ++j) {
    a[2 * j]     = bf2f((unsigned short)(u[j] & 0xffffu));
    a[2 * j + 1] = bf2f((unsigned short)(u[j] >> 16));
  }
  if (!tail) { a[8] = -1e30f; a[9] = -1e30f; }
  float mx = a[0];
  #pragma unroll
  for (int j = 1; j < 10; ++j) mx = fmaxf(mx, a[j]);
  #pragma unroll
  for (int i = 32; i >= 1; i >>= 1) mx = fmaxf(mx, __shfl_xor(mx, i));
  float sum = 0.f;
  #pragma unroll
  for (int j = 0; j < 8; ++j) { a[j] = __expf(a[j] - mx); sum += a[j]; }
  if (tail) { a[8] = __expf(a[8] - mx); a[9] = __expf(a[9] - mx); sum += a[8] + a[9]; }
  #pragma unroll
  for (int i = 32; i >= 1; i >>= 1) sum += __shfl_xor(sum, i);
  const float inv = 1.0f / sum;
  #pragma unroll
  for (int j = 0; j < 4; ++j)
    rp[lane + 64 * j] = (unsigned int)f2bf(a[2 * j] * inv) |
                        ((unsigned int)f2bf(a[2 * j + 1] * inv) << 16);
  if (tail)
    rp[lane + 256] = (unsigned int)f2bf(a[8] * inv) | ((unsigned int)f2bf(a[9] * inv) << 16);
}

// ---------- LayerNorm over 768, in place on fp32 rows ----------
__global__ __launch_bounds__(256) void k_layernorm768(float* O, const float* __restrict__ gamma,
                                                      const float* __restrict__ beta) {
  const int row = blockIdx.x;
  float* p = O + (size_t)row * 768;
  const int t = threadIdx.x;
  const int lane = t & 63, wave = t >> 6;
  const float x0 = p[t], x1 = p[t + 256], x2 = p[t + 512];
  float s = x0 + x1 + x2;
  float q = x0 * x0 + x1 * x1 + x2 * x2;
  #pragma unroll
  for (int i = 32; i >= 1; i >>= 1) { s += __shfl_xor(s, i); q += __shfl_xor(q, i); }
  __shared__ float rs[4], rq[4];
  if (lane == 0) { rs[wave] = s; rq[wave] = q; }
  __syncthreads();
  s = rs[0] + rs[1] + rs[2] + rs[3];
  q = rq[0] + rq[1] + rq[2] + rq[3];
  const float mu = s * (1.0f / 768.0f);
  const float var = q * (1.0f / 768.0f) - mu * mu;
  const float inv = rsqrtf(var + 1e-5f);
  p[t]       = (x0 - mu) * inv * gamma[t]       + beta[t];
  p[t + 256] = (x1 - mu) * inv * gamma[t + 256] + beta[t + 256];
  p[t + 512] = (x2 - mu) * inv * gamma[t + 512] + beta[t + 512];
}

// ---------- host ----------
extern "C" void kernel_launch(void* const* d_in, const int* in_sizes, int n_in,
                              void* d_out, int out_size, void* d_ws, size_t ws_size,
                              hipStream_t stream) {
  const float* text  = (const float*)d_in[0];
  const float* image = (const float*)d_in[1];
  const float* wq = (const float*)d_in[2];  const float* bq = (const float*)d_in[3];
  const float* wk = (const float*)d_in[4];  const float* bk = (const float*)d_in[5];
  const float* wv = (const float*)d_in[6];  const float* bv = (const float*)d_in[7];
  const float* wr = (const float*)d_in[8];  const float* br = (const float*)d_in[9];
  const float* w1 = (const float*)d_in[10]; const float* b1 = (const float*)d_in[11];
  const float* w2 = (const float*)d_in[12]; const float* b2 = (const float*)d_in[13];
  const float* gamma = (const float*)d_in[14]; const float* beta = (const float*)d_in[15];

  uint8_t* ws = (uint8_t*)d_ws;
  // region0 (33.55 MB): Tbf+Ibf early, reused for X later (lifetimes disjoint)
  constexpr size_t o_Tbf = 0;
  constexpr size_t o_Ibf = 12582912;                 // 8192*768*2
  constexpr size_t o_X   = 0;                        // 8192*2048*2 = 33554432
  constexpr size_t o_Q   = 33554432;
  constexpr size_t o_Kb  = o_Q   + 33554432;         // 8192*2048*2
  constexpr size_t o_Vt  = o_Kb  + 37748736;         // 9216*2048*2
  constexpr size_t o_S   = o_Vt  + 37748736;         // 16*8*256*576*2
  constexpr size_t o_wqT = o_S   + 75497472;         // 65536*576*2
  constexpr size_t o_wkT = o_wqT + 3145728;
  constexpr size_t o_wvT = o_wkT + 4194304;
  constexpr size_t o_wrT = o_wvT + 4194304;
  constexpr size_t o_w1T = o_wrT + 3145728;
  constexpr size_t o_w2T = o_w1T + 196608;
  constexpr size_t o_OutB= o_w2T + 196608;
  constexpr size_t o_H   = o_OutB+ 12582912;         // 8192*768*2
  // total = o_H + 2097152 = 247,857,152 bytes

  unsigned short* Tbf  = (unsigned short*)(ws + o_Tbf);
  unsigned short* Ibf  = (unsigned short*)(ws + o_Ibf);
  unsigned short* Xb   = (unsigned short*)(ws + o_X);
  unsigned short* Qb   = (unsigned short*)(ws + o_Q);
  unsigned short* Kb   = (unsigned short*)(ws + o_Kb);
  unsigned short* Vt   = (unsigned short*)(ws + o_Vt);
  unsigned short* Sb   = (unsigned short*)(ws + o_S);
  unsigned short* wqT  = (unsigned short*)(ws + o_wqT);
  unsigned short* wkT  = (unsigned short*)(ws + o_wkT);
  unsigned short* wvT  = (unsigned short*)(ws + o_wvT);
  unsigned short* wrT  = (unsigned short*)(ws + o_wrT);
  unsigned short* w1T  = (unsigned short*)(ws + o_w1T);
  unsigned short* w2T  = (unsigned short*)(ws + o_w2T);
  unsigned short* OutB = (unsigned short*)(ws + o_OutB);
  unsigned short* Hb   = (unsigned short*)(ws + o_H);
  float* OutF = (float*)d_out;

  const dim3 blk(256);

  // --- prep: convert inputs, transpose weights (fp32 -> bf16) ---
  k_f32_to_bf16<<<dim3(6144), blk, 0, stream>>>(text,  Tbf, 1572864);
  k_f32_to_bf16<<<dim3(9216), blk, 0, stream>>>(image, Ibf, 2359296);
  k_transpose_to_bf16<<<dim3(64, 24), blk, 0, stream>>>(wq, wqT, 768, 2048);
  k_transpose_to_bf16<<<dim3(64, 32), blk, 0, stream>>>(wk, wkT, 1024, 2048);
  k_transpose_to_bf16<<<dim3(64, 32), blk, 0, stream>>>(wv, wvT, 1024, 2048);
  k_transpose_to_bf16<<<dim3(24, 64), blk, 0, stream>>>(wr, wrT, 2048, 768);
  k_transpose_to_bf16<<<dim3(4, 24),  blk, 0, stream>>>(w1, w1T, 768, 128);
  k_transpose_to_bf16<<<dim3(24, 4),  blk, 0, stream>>>(w2, w2T, 128, 768);

  // --- Q = text @ wq + bq : [8192,2048] ---
  k_gemm<128, 128, EPI_BIAS><<<dim3(16, 64, 1), blk, 0, stream>>>(
      Tbf, wqT, 768, 768, 24, 0, 0, 0, 0, 0, 0, Qb, nullptr, bq, nullptr, 2048);
  // --- K = image @ wk + bk : [9216,2048] ---
  k_gemm<128, 128, EPI_BIAS><<<dim3(16, 72, 1), blk, 0, stream>>>(
      Ibf, wkT, 1024, 1024, 32, 0, 0, 0, 0, 0, 0, Kb, nullptr, bk, nullptr, 2048);
  // --- V = image @ wv + bv, written transposed as Vt[b][h][d][li] ---
  k_gemm<128, 128, EPI_VT><<<dim3(16, 72, 1), blk, 0, stream>>>(
      Ibf, wvT, 1024, 1024, 32, 0, 0, 0, 0, 0, 0, Vt, nullptr, bv, nullptr, 0);

  // --- S = Q @ K^T / 16, batched over 128 (b,h); [512,576] each ---
  k_gemm<128, 64, EPI_SCALE><<<dim3(9, 4, 128), blk, 0, stream>>>(
      Qb, Kb, 2048, 2048, 8,
      1048576, 256,        // A: b-stride 512*2048, h-stride 256
      1179648, 256,        // B: b-stride 576*2048, h-stride 256
      2359296, 294912,     // C: (b,h) linear in 512*576
      Sb, nullptr, nullptr, nullptr, 576);

  // --- softmax rows (65536 rows x 576), in place ---
  k_softmax576<<<dim3(16384), blk, 0, stream>>>(Sb);

  // --- X = P @ V : batched [512,256] per (b,h), stored [8192,2048] ---
  k_gemm<128, 128, EPI_PLAIN><<<dim3(2, 4, 128), blk, 0, stream>>>(
      Sb, Vt, 576, 576, 18,
      2359296, 294912,     // A = P
      1179648, 147456,     // B = Vt per (b,h): 256*576
      1048576, 256,        // C = X[b*512+q][h*256+d]
      Xb, nullptr, nullptr, nullptr, 2048);

  // --- out = X @ wr + br : fp32 into d_out + bf16 copy for FF ---
  k_gemm<128, 128, EPI_DUAL><<<dim3(6, 64, 1), blk, 0, stream>>>(
      Xb, wrT, 2048, 2048, 64, 0, 0, 0, 0, 0, 0, OutF, OutB, br, nullptr, 768);

  // --- h = relu(out @ w1 + b1) : [8192,128] ---
  k_gemm<128, 128, EPI_RELU><<<dim3(1, 64, 1), blk, 0, stream>>>(
      OutB, w1T, 768, 768, 24, 0, 0, 0, 0, 0, 0, Hb, nullptr, b1, nullptr, 128);

  // --- out += h @ w2 + b2 (residual read from d_out, write back pre-LN) ---
  k_gemm<128, 128, EPI_RES><<<dim3(6, 64, 1), blk, 0, stream>>>(
      Hb, w2T, 128, 128, 4, 0, 0, 0, 0, 0, 0, OutF, nullptr, b2, (const float*)d_out, 768);

  // --- LayerNorm in place on d_out ---
  k_layernorm768<<<dim3(8192), blk, 0, stream>>>(OutF, gamma, beta);

  (void)in_sizes; (void)n_in; (void)out_size; (void)ws_size;
}